// Round 2
// baseline (1085.963 us; speedup 1.0000x reference)
//
#include <hip/hip_runtime.h>
#include <hip/hip_bf16.h>

#define EMBED  64
#define TLEN   256
#define BATCH  32
#define NROWS  (BATCH*TLEN)      // 8192
#define VOCAB  50257
#define VPAD   51200             // 50 * 1024, zero-padded B rows
#define LNEPS  1e-5f

typedef __attribute__((ext_vector_type(8))) short  bf16x8;
typedef __attribute__((ext_vector_type(4))) float  f32x4;
typedef __attribute__((ext_vector_type(4))) unsigned int u32x4;

static __device__ __forceinline__ unsigned short f2bf(float f) {
    unsigned int u = __float_as_uint(f);
    unsigned int r = (u + 0x7fffu + ((u >> 16) & 1u)) >> 16;   // RNE
    return (unsigned short)r;
}

// ---------------- fc_w [64][VOCAB] f32  ->  wt [VPAD][64] bf16 (transposed, zero-padded)
__global__ __launch_bounds__(256) void prep_wt(const float* __restrict__ fcw,
                                               unsigned short* __restrict__ wt) {
    int n = blockIdx.x * 256 + threadIdx.x;
    if (n >= VPAD) return;
    unsigned int packed[32];
    if (n < VOCAB) {
        #pragma unroll
        for (int k2 = 0; k2 < 32; ++k2) {
            unsigned int lo = f2bf(fcw[(size_t)(2*k2)   * VOCAB + n]);
            unsigned int hi = f2bf(fcw[(size_t)(2*k2+1) * VOCAB + n]);
            packed[k2] = lo | (hi << 16);
        }
    } else {
        #pragma unroll
        for (int k2 = 0; k2 < 32; ++k2) packed[k2] = 0u;
    }
    u32x4* dst = (u32x4*)(wt + (size_t)n * 64);
    #pragma unroll
    for (int i = 0; i < 8; ++i) {
        u32x4 v = { packed[4*i], packed[4*i+1], packed[4*i+2], packed[4*i+3] };
        dst[i] = v;
    }
}

// ---------------- embed gather + pos add -> h ; LN1 -> hn   (one wave per row)
__global__ __launch_bounds__(256) void embed_ln(const int* __restrict__ x,
                                                const float* __restrict__ ew,
                                                const float* __restrict__ pw,
                                                const float* __restrict__ g,
                                                const float* __restrict__ bb,
                                                float* __restrict__ h,
                                                float* __restrict__ hn) {
    int row = blockIdx.x * 4 + (threadIdx.x >> 6);
    int e   = threadIdx.x & 63;
    int tok = x[row];
    float v = ew[(size_t)tok * 64 + e] + pw[(size_t)(row & 255) * 64 + e];
    h[(size_t)row * 64 + e] = v;
    float s = v;
    #pragma unroll
    for (int m = 32; m >= 1; m >>= 1) s += __shfl_xor(s, m, 64);
    float mu = s * (1.f/64.f);
    float d  = v - mu;
    float s2 = d * d;
    #pragma unroll
    for (int m = 32; m >= 1; m >>= 1) s2 += __shfl_xor(s2, m, 64);
    float var = s2 * (1.f/64.f);
    hn[(size_t)row * 64 + e] = d * rsqrtf(var + LNEPS) * g[e] + bb[e];
}

// ---------------- Q,K,V GEMMs.  wave0->Q, wave1->K (stored transposed), wave2->V
__global__ __launch_bounds__(192) void qkv(const float* __restrict__ hn,
                                           const float* __restrict__ wq,
                                           const float* __restrict__ wk,
                                           const float* __restrict__ wv,
                                           float* __restrict__ q,
                                           float* __restrict__ kt,
                                           float* __restrict__ v) {
    int wave = threadIdx.x >> 6;     // 0..2
    int j    = threadIdx.x & 63;
    const float* W = (wave == 0) ? wq : ((wave == 1) ? wk : wv);
    int m0 = blockIdx.x * 16;
    for (int r = 0; r < 16; ++r) {
        int m = m0 + r;
        const float* hr = hn + (size_t)m * 64;   // uniform -> scalar loads
        float acc = 0.f;
        #pragma unroll
        for (int e = 0; e < 64; ++e) acc += hr[e] * W[e * 64 + j];
        if (wave == 0)      q[(size_t)m * 64 + j] = acc;
        else if (wave == 1) {
            int b = m >> 8, t = m & 255;
            kt[((size_t)b * 64 + j) * 256 + t] = acc;
        } else              v[(size_t)m * 64 + j] = acc;
    }
}

// ---------------- scores (QK^T/8, causal) + softmax -> P f32.  4 query rows per block.
__global__ __launch_bounds__(256) void attn_sm(const float* __restrict__ q,
                                               const float* __restrict__ kt,
                                               float* __restrict__ p) {
    int b   = blockIdx.y;            // 0..31
    int m4  = blockIdx.x;            // 0..63
    int key = threadIdx.x;           // 0..255
    int wave = key >> 6, lane = key & 63;
    const float* ktb = kt + (size_t)b * 64 * 256;
    const float* qb  = q  + ((size_t)b * 256 + m4 * 4) * 64;   // 4 rows, uniform
    float s0=0.f, s1=0.f, s2=0.f, s3=0.f;
    for (int e = 0; e < 64; ++e) {
        float kv = ktb[e * 256 + key];
        s0 += qb[e]       * kv;
        s1 += qb[64 + e]  * kv;
        s2 += qb[128 + e] * kv;
        s3 += qb[192 + e] * kv;
    }
    float sv[4] = { s0*0.125f, s1*0.125f, s2*0.125f, s3*0.125f };
    __shared__ float redm[4][4], reds[4][4];
    float pe[4];
    #pragma unroll
    for (int r = 0; r < 4; ++r) {
        int mrow = m4 * 4 + r;
        float xv = (key <= mrow) ? sv[r] : -1e30f;
        sv[r] = xv;
        float wm = xv;
        #pragma unroll
        for (int mm = 32; mm >= 1; mm >>= 1) wm = fmaxf(wm, __shfl_xor(wm, mm, 64));
        if (lane == 0) redm[wave][r] = wm;
    }
    __syncthreads();
    #pragma unroll
    for (int r = 0; r < 4; ++r) {
        float M = fmaxf(fmaxf(redm[0][r], redm[1][r]), fmaxf(redm[2][r], redm[3][r]));
        float e_ = expf(sv[r] - M);
        pe[r] = e_;
        float ws = e_;
        #pragma unroll
        for (int mm = 32; mm >= 1; mm >>= 1) ws += __shfl_xor(ws, mm, 64);
        if (lane == 0) reds[wave][r] = ws;
    }
    __syncthreads();
    float* pb = p + ((size_t)b * 256 + m4 * 4) * 256;
    #pragma unroll
    for (int r = 0; r < 4; ++r) {
        float S = reds[0][r] + reds[1][r] + reds[2][r] + reds[3][r];
        pb[r * 256 + key] = pe[r] / S;
    }
}

// ---------------- ctx = P@V ; h2 = h + ctx ; LNf -> hf bf16.  One wave per row.
__global__ __launch_bounds__(256) void ctx_lnf(const float* __restrict__ p,
                                               const float* __restrict__ v,
                                               const float* __restrict__ h,
                                               const float* __restrict__ g,
                                               const float* __restrict__ bb,
                                               unsigned short* __restrict__ hf) {
    int m = blockIdx.x * 4 + (threadIdx.x >> 6);
    int n = threadIdx.x & 63;
    int b = m >> 8, t = m & 255;
    const float* pr = p + ((size_t)b * 256 + t) * 256;   // uniform -> scalar loads
    const float* vb = v + (size_t)b * 256 * 64;
    float acc = 0.f;
    for (int key = 0; key <= t; ++key)
        acc += pr[key] * vb[key * 64 + n];
    float h2 = h[(size_t)m * 64 + n] + acc;
    float s = h2;
    #pragma unroll
    for (int mm = 32; mm >= 1; mm >>= 1) s += __shfl_xor(s, mm, 64);
    float mu = s * (1.f/64.f);
    float d  = h2 - mu;
    float s2 = d * d;
    #pragma unroll
    for (int mm = 32; mm >= 1; mm >>= 1) s2 += __shfl_xor(s2, mm, 64);
    float var = s2 * (1.f/64.f);
    hf[(size_t)m * 64 + n] = f2bf(d * rsqrtf(var + LNEPS) * g[n] + bb[n]);
}

// ---------------- logits = hf @ fc_w + fc_b  (bf16 MFMA, f32 out)
// Block tile: 16 rows x 1024 cols (4KB contiguous per row -> full L2 lines).
// 4 waves side-by-side in n; wave tile 16m x 256n; grid.x = row tiles so all
// XCDs share one B column-stripe (128KB) in their L2s.
__global__ __launch_bounds__(256) void final_gemm(const unsigned short* __restrict__ hf,
                                                  const unsigned short* __restrict__ wt,
                                                  const float* __restrict__ bias,
                                                  float* __restrict__ out) {
    int mb = blockIdx.x;             // 0..511
    int nb = blockIdx.y;             // 0..49
    int wave = threadIdx.x >> 6, lane = threadIdx.x & 63;
    int l15 = lane & 15, lk = lane >> 4;
    int m0 = mb * 16;
    int n0 = nb * 1024 + wave * 256;
    const bf16x8* arow = (const bf16x8*)(hf + (size_t)(m0 + l15) * 64);
    bf16x8 a0 = arow[lk];        // k 0..31
    bf16x8 a1 = arow[4 + lk];    // k 32..63
    // per-lane output base: rows m0+lk*4+0..3, col n0+l15 (+nt*16)
    float* ob = out + (size_t)(m0 + lk * 4) * VOCAB + n0 + l15;
    #pragma unroll
    for (int nt = 0; nt < 16; ++nt) {
        const bf16x8* brow = (const bf16x8*)(wt + (size_t)(n0 + nt * 16 + l15) * 64);
        f32x4 c = {0.f, 0.f, 0.f, 0.f};
        c = __builtin_amdgcn_mfma_f32_16x16x32_bf16(a0, brow[lk],     c, 0, 0, 0);
        c = __builtin_amdgcn_mfma_f32_16x16x32_bf16(a1, brow[4 + lk], c, 0, 0, 0);
        int col = n0 + nt * 16 + l15;
        if (col < VOCAB) {
            float bv = bias[col];
            float* op = ob + nt * 16;
            op[0]             = c[0] + bv;
            op[VOCAB]         = c[1] + bv;
            op[2 * VOCAB]     = c[2] + bv;
            op[3 * (size_t)VOCAB] = c[3] + bv;
        }
    }
}

extern "C" void kernel_launch(void* const* d_in, const int* in_sizes, int n_in,
                              void* d_out, int out_size, void* d_ws, size_t ws_size,
                              hipStream_t stream) {
    const int*   x    = (const int*)  d_in[0];
    const float* ew   = (const float*)d_in[1];
    const float* pw   = (const float*)d_in[2];
    const float* ln1g = (const float*)d_in[3];
    const float* ln1b = (const float*)d_in[4];
    const float* wq   = (const float*)d_in[5];
    const float* wk   = (const float*)d_in[6];
    const float* wv   = (const float*)d_in[7];
    const float* lnfg = (const float*)d_in[8];
    const float* lnfb = (const float*)d_in[9];
    const float* fcw  = (const float*)d_in[10];
    const float* fcb  = (const float*)d_in[11];
    float* out = (float*)d_out;

    char* ws = (char*)d_ws;
    float*          h  = (float*)(ws + 0);                    //  0..2 MB
    float*          hn = (float*)(ws + (2u<<20));             //  2..4 MB (dead after qkv)
    unsigned short* hf = (unsigned short*)(ws + (2u<<20));    //  reuses hn slot (1 MB)
    float*          q  = (float*)(ws + (4u<<20));             //  4..6 MB
    float*          kt = (float*)(ws + (6u<<20));             //  6..8 MB
    float*          v  = (float*)(ws + (8u<<20));             //  8..10 MB
    float*          p  = (float*)(ws + (10u<<20));            // 10..18 MB
    unsigned short* wt = (unsigned short*)(ws + (18u<<20));   // 18..24.25 MB

    prep_wt  <<<dim3(VPAD / 256),  dim3(256), 0, stream>>>(fcw, wt);
    embed_ln <<<dim3(NROWS / 4),   dim3(256), 0, stream>>>(x, ew, pw, ln1g, ln1b, h, hn);
    qkv      <<<dim3(NROWS / 16),  dim3(192), 0, stream>>>(hn, wq, wk, wv, q, kt, v);
    attn_sm  <<<dim3(64, 32),      dim3(256), 0, stream>>>(q, kt, p);
    ctx_lnf  <<<dim3(NROWS / 4),   dim3(256), 0, stream>>>(p, v, h, lnfg, lnfb, hf);
    final_gemm<<<dim3(NROWS / 16, VPAD / 1024), dim3(256), 0, stream>>>(hf, wt, fcb, out);
}

// Round 3
// 643.813 us; speedup vs baseline: 1.6868x; 1.6868x over previous
//
#include <hip/hip_runtime.h>
#include <hip/hip_bf16.h>

#define EMBED  64
#define TLEN   256
#define BATCH  32
#define NROWS  (BATCH*TLEN)      // 8192
#define VOCAB  50257
#define BCOLS  512
#define NB     99                // col stripes
#define VPAD   (NB*BCOLS)        // 50688, zero-padded B rows
#define LNEPS  1e-5f

typedef __attribute__((ext_vector_type(8))) short  bf16x8;
typedef __attribute__((ext_vector_type(4))) float  f32x4;
typedef __attribute__((ext_vector_type(4))) unsigned int u32x4;

static __device__ __forceinline__ unsigned short f2bf(float f) {
    unsigned int u = __float_as_uint(f);
    unsigned int r = (u + 0x7fffu + ((u >> 16) & 1u)) >> 16;   // RNE
    return (unsigned short)r;
}

// ---------------- fc_w [64][VOCAB] f32  ->  wt [VPAD][64] bf16 (transposed, zero-padded)
__global__ __launch_bounds__(256) void prep_wt(const float* __restrict__ fcw,
                                               unsigned short* __restrict__ wt) {
    int n = blockIdx.x * 256 + threadIdx.x;
    if (n >= VPAD) return;
    unsigned int packed[32];
    if (n < VOCAB) {
        #pragma unroll
        for (int k2 = 0; k2 < 32; ++k2) {
            unsigned int lo = f2bf(fcw[(size_t)(2*k2)   * VOCAB + n]);
            unsigned int hi = f2bf(fcw[(size_t)(2*k2+1) * VOCAB + n]);
            packed[k2] = lo | (hi << 16);
        }
    } else {
        #pragma unroll
        for (int k2 = 0; k2 < 32; ++k2) packed[k2] = 0u;
    }
    u32x4* dst = (u32x4*)(wt + (size_t)n * 64);
    #pragma unroll
    for (int i = 0; i < 8; ++i) {
        u32x4 v = { packed[4*i], packed[4*i+1], packed[4*i+2], packed[4*i+3] };
        dst[i] = v;
    }
}

// ---------------- embed gather + pos add -> h ; LN1 -> hn   (one wave per row)
__global__ __launch_bounds__(256) void embed_ln(const int* __restrict__ x,
                                                const float* __restrict__ ew,
                                                const float* __restrict__ pw,
                                                const float* __restrict__ g,
                                                const float* __restrict__ bb,
                                                float* __restrict__ h,
                                                float* __restrict__ hn) {
    int row = blockIdx.x * 4 + (threadIdx.x >> 6);
    int e   = threadIdx.x & 63;
    int tok = x[row];
    float v = ew[(size_t)tok * 64 + e] + pw[(size_t)(row & 255) * 64 + e];
    h[(size_t)row * 64 + e] = v;
    float s = v;
    #pragma unroll
    for (int m = 32; m >= 1; m >>= 1) s += __shfl_xor(s, m, 64);
    float mu = s * (1.f/64.f);
    float d  = v - mu;
    float s2 = d * d;
    #pragma unroll
    for (int m = 32; m >= 1; m >>= 1) s2 += __shfl_xor(s2, m, 64);
    float var = s2 * (1.f/64.f);
    hn[(size_t)row * 64 + e] = d * rsqrtf(var + LNEPS) * g[e] + bb[e];
}

// ---------------- Q,K,V GEMMs.  wave0->Q, wave1->K (stored transposed), wave2->V
__global__ __launch_bounds__(192) void qkv(const float* __restrict__ hn,
                                           const float* __restrict__ wq,
                                           const float* __restrict__ wk,
                                           const float* __restrict__ wv,
                                           float* __restrict__ q,
                                           float* __restrict__ kt,
                                           float* __restrict__ v) {
    int wave = threadIdx.x >> 6;     // 0..2
    int j    = threadIdx.x & 63;
    const float* W = (wave == 0) ? wq : ((wave == 1) ? wk : wv);
    int m0 = blockIdx.x * 16;
    for (int r = 0; r < 16; ++r) {
        int m = m0 + r;
        const float* hr = hn + (size_t)m * 64;   // uniform -> scalar loads
        float acc = 0.f;
        #pragma unroll
        for (int e = 0; e < 64; ++e) acc += hr[e] * W[e * 64 + j];
        if (wave == 0)      q[(size_t)m * 64 + j] = acc;
        else if (wave == 1) {
            int b = m >> 8, t = m & 255;
            kt[((size_t)b * 64 + j) * 256 + t] = acc;
        } else              v[(size_t)m * 64 + j] = acc;
    }
}

// ---------------- scores (QK^T/8, causal) + softmax -> P f32.  4 query rows per block.
__global__ __launch_bounds__(256) void attn_sm(const float* __restrict__ q,
                                               const float* __restrict__ kt,
                                               float* __restrict__ p) {
    int b   = blockIdx.y;            // 0..31
    int m4  = blockIdx.x;            // 0..63
    int key = threadIdx.x;           // 0..255
    int wave = key >> 6, lane = key & 63;
    const float* ktb = kt + (size_t)b * 64 * 256;
    const float* qb  = q  + ((size_t)b * 256 + m4 * 4) * 64;   // 4 rows, uniform
    float s0=0.f, s1=0.f, s2=0.f, s3=0.f;
    for (int e = 0; e < 64; ++e) {
        float kv = ktb[e * 256 + key];
        s0 += qb[e]       * kv;
        s1 += qb[64 + e]  * kv;
        s2 += qb[128 + e] * kv;
        s3 += qb[192 + e] * kv;
    }
    float sv[4] = { s0*0.125f, s1*0.125f, s2*0.125f, s3*0.125f };
    __shared__ float redm[4][4], reds[4][4];
    float pe[4];
    #pragma unroll
    for (int r = 0; r < 4; ++r) {
        int mrow = m4 * 4 + r;
        float xv = (key <= mrow) ? sv[r] : -1e30f;
        sv[r] = xv;
        float wm = xv;
        #pragma unroll
        for (int mm = 32; mm >= 1; mm >>= 1) wm = fmaxf(wm, __shfl_xor(wm, mm, 64));
        if (lane == 0) redm[wave][r] = wm;
    }
    __syncthreads();
    #pragma unroll
    for (int r = 0; r < 4; ++r) {
        float M = fmaxf(fmaxf(redm[0][r], redm[1][r]), fmaxf(redm[2][r], redm[3][r]));
        float e_ = expf(sv[r] - M);
        pe[r] = e_;
        float ws = e_;
        #pragma unroll
        for (int mm = 32; mm >= 1; mm >>= 1) ws += __shfl_xor(ws, mm, 64);
        if (lane == 0) reds[wave][r] = ws;
    }
    __syncthreads();
    float* pb = p + ((size_t)b * 256 + m4 * 4) * 256;
    #pragma unroll
    for (int r = 0; r < 4; ++r) {
        float S = reds[0][r] + reds[1][r] + reds[2][r] + reds[3][r];
        pb[r * 256 + key] = pe[r] / S;
    }
}

// ---------------- ctx = P@V ; h2 = h + ctx ; LNf -> hf bf16.  One wave per row.
__global__ __launch_bounds__(256) void ctx_lnf(const float* __restrict__ p,
                                               const float* __restrict__ v,
                                               const float* __restrict__ h,
                                               const float* __restrict__ g,
                                               const float* __restrict__ bb,
                                               unsigned short* __restrict__ hf) {
    int m = blockIdx.x * 4 + (threadIdx.x >> 6);
    int n = threadIdx.x & 63;
    int b = m >> 8, t = m & 255;
    const float* pr = p + ((size_t)b * 256 + t) * 256;   // uniform -> scalar loads
    const float* vb = v + (size_t)b * 256 * 64;
    float acc = 0.f;
    for (int key = 0; key <= t; ++key)
        acc += pr[key] * vb[key * 64 + n];
    float h2 = h[(size_t)m * 64 + n] + acc;
    float s = h2;
    #pragma unroll
    for (int mm = 32; mm >= 1; mm >>= 1) s += __shfl_xor(s, mm, 64);
    float mu = s * (1.f/64.f);
    float d  = h2 - mu;
    float s2 = d * d;
    #pragma unroll
    for (int mm = 32; mm >= 1; mm >>= 1) s2 += __shfl_xor(s2, mm, 64);
    float var = s2 * (1.f/64.f);
    hf[(size_t)m * 64 + n] = f2bf(d * rsqrtf(var + LNEPS) * g[n] + bb[n]);
}

// ---------------- logits = hf @ fc_w + fc_b  (bf16 MFMA, f32 out)
// Block tile: 16 rows x 512 cols. MFMA accumulators staged through LDS so the
// store phase emits 256B-contiguous dwordx4 runs (full 128B lines from one
// instruction stream). Grid is 1-D with an XCD-aware remap: each XCD owns a
// contiguous 1024-row slab; within it, blocks sweep 8 bands x stripes so
// concurrent writes per XCD are address-adjacent and wt stripes stay in L2.
__global__ __launch_bounds__(256) void final_gemm(const unsigned short* __restrict__ hf,
                                                  const unsigned short* __restrict__ wt,
                                                  const float* __restrict__ bias,
                                                  float* __restrict__ out) {
    int bid = blockIdx.x;                  // 0..50687  (= 8 * 8 * 99 * 8)
    int xcd = bid & 7;
    int j   = bid >> 3;                    // 0..6335
    int g   = j / 792;                     // 0..7   (band group within slab)
    int rj  = j - g * 792;                 // 0..791
    int nb  = rj >> 3;                     // 0..98  (stripe; advances every 8)
    int mb  = xcd * 64 + g * 8 + (rj & 7); // 0..511 (band)

    int tid  = threadIdx.x;
    int wave = tid >> 6, lane = tid & 63;
    int l15 = lane & 15, lk = lane >> 4;
    int m0 = mb * 16;

    __shared__ float lds[16 * 520];        // [row][520] (pad 8 floats)

    const bf16x8* arow = (const bf16x8*)(hf + (size_t)(m0 + l15) * 64);
    bf16x8 a0 = arow[lk];        // k 0..31
    bf16x8 a1 = arow[4 + lk];    // k 32..63

    #pragma unroll
    for (int nt = 0; nt < 8; ++nt) {
        int lcol = wave * 128 + nt * 16 + l15;         // 0..511
        int col  = nb * BCOLS + lcol;
        const bf16x8* brow = (const bf16x8*)(wt + (size_t)col * 64);
        f32x4 c = {0.f, 0.f, 0.f, 0.f};
        c = __builtin_amdgcn_mfma_f32_16x16x32_bf16(a0, brow[lk],     c, 0, 0, 0);
        c = __builtin_amdgcn_mfma_f32_16x16x32_bf16(a1, brow[4 + lk], c, 0, 0, 0);
        float bv = (col < VOCAB) ? bias[col] : 0.f;
        #pragma unroll
        for (int r = 0; r < 4; ++r)
            lds[(lk * 4 + r) * 520 + lcol] = c[r] + bv;
    }
    __syncthreads();

    // store phase: thread t -> row t>>4; run i: 16 lanes cover 256B contiguous
    int row = tid >> 4, cc = tid & 15;
    float* orow = out + (size_t)(m0 + row) * VOCAB + nb * BCOLS;
    const float* lrow = lds + row * 520;
    #pragma unroll
    for (int i = 0; i < 8; ++i) {
        int lcol = i * 64 + cc * 4;
        f32x4 vv = *(const f32x4*)(lrow + lcol);
        int cs = nb * BCOLS + lcol;
        if (cs + 4 <= VOCAB) {
            *(f32x4*)(orow + lcol) = vv;
        } else {
            #pragma unroll
            for (int e = 0; e < 4; ++e)
                if (cs + e < VOCAB) orow[lcol + e] = vv[e];
        }
    }
}

extern "C" void kernel_launch(void* const* d_in, const int* in_sizes, int n_in,
                              void* d_out, int out_size, void* d_ws, size_t ws_size,
                              hipStream_t stream) {
    const int*   x    = (const int*)  d_in[0];
    const float* ew   = (const float*)d_in[1];
    const float* pw   = (const float*)d_in[2];
    const float* ln1g = (const float*)d_in[3];
    const float* ln1b = (const float*)d_in[4];
    const float* wq   = (const float*)d_in[5];
    const float* wk   = (const float*)d_in[6];
    const float* wv   = (const float*)d_in[7];
    const float* lnfg = (const float*)d_in[8];
    const float* lnfb = (const float*)d_in[9];
    const float* fcw  = (const float*)d_in[10];
    const float* fcb  = (const float*)d_in[11];
    float* out = (float*)d_out;

    char* ws = (char*)d_ws;
    float*          h  = (float*)(ws + 0);                    //  0..2 MB
    float*          hn = (float*)(ws + (2u<<20));             //  2..4 MB (dead after qkv)
    unsigned short* hf = (unsigned short*)(ws + (2u<<20));    //  reuses hn slot (1 MB)
    float*          q  = (float*)(ws + (4u<<20));             //  4..6 MB
    float*          kt = (float*)(ws + (6u<<20));             //  6..8 MB
    float*          v  = (float*)(ws + (8u<<20));             //  8..10 MB
    float*          p  = (float*)(ws + (10u<<20));            // 10..18 MB
    unsigned short* wt = (unsigned short*)(ws + (18u<<20));   // 18..24.2 MB

    prep_wt  <<<dim3(VPAD / 256),  dim3(256), 0, stream>>>(fcw, wt);
    embed_ln <<<dim3(NROWS / 4),   dim3(256), 0, stream>>>(x, ew, pw, ln1g, ln1b, h, hn);
    qkv      <<<dim3(NROWS / 16),  dim3(192), 0, stream>>>(hn, wq, wk, wv, q, kt, v);
    attn_sm  <<<dim3(64, 32),      dim3(256), 0, stream>>>(q, kt, p);
    ctx_lnf  <<<dim3(NROWS / 4),   dim3(256), 0, stream>>>(p, v, h, lnfg, lnfb, hf);
    final_gemm<<<dim3(8 * 8 * NB * 8), dim3(256), 0, stream>>>(hf, wt, fcb, out);
}